// Round 13
// baseline (231.601 us; speedup 1.0000x reference)
//
#include <hip/hip_runtime.h>
#include <math.h>

#define B_   128
#define L_   128
#define E_   300
#define P_   50
#define FN_  256
#define H2_  100
#define LAB_ 19

typedef unsigned short ushort_t;
typedef __attribute__((ext_vector_type(8))) short bf16x8;
typedef __attribute__((ext_vector_type(4))) short bf16x4;
typedef __attribute__((ext_vector_type(4))) short short4v;
typedef __attribute__((ext_vector_type(4))) float f32x4;

// folded-K geometry (stride-300/100): word K=(k+2)*300 pad64, pos K=k*100 pad64
#define KW0 1536
#define KW1 1856
#define KW2 2112
#define KP0 320
#define KP1 448
#define KP2 512
#define KC  960

#define WE_STRIDE  40960   // per-b we_flat elems (130x300 + zero tail)
#define POS_STRIDE 13312   // per-b posflat elems (128x100 + zero tail)

#define N_WE   (B_ * WE_STRIDE)
#define N_POS  (B_ * POS_STRIDE)
#define N_WFW  (FN_ * (KW0 + KW1 + KW2))
#define N_WFP  (FN_ * (KP0 + KP1 + KP2))
#define N_CORR (3 * FN_ * KC)

#define WEB  (B_ * 35)
#define POSB (B_ * 17)
#define WFWB (N_WFW / 2048)
#define WFPB (N_WFP / 2048)
#define CORB (N_CORR / 2048)
#define SETUP_BLOCKS (WEB + POSB + WFWB + WFPB + CORB)

__device__ __forceinline__ ushort_t f2bf(float x) {
    unsigned u = __float_as_uint(x);
    u += 0x7FFFu + ((u >> 16) & 1u);
    return (ushort_t)(u >> 16);
}

__device__ __forceinline__ void gld_lds16(const void* g, void* lds_uniform) {
    __builtin_amdgcn_global_load_lds(
        (const __attribute__((address_space(1))) void*)g,
        (__attribute__((address_space(3))) void*)lds_uniform,
        16, 0, 0);
}

// 8 bf16 via two 8B loads (rows stride 600/200B: only 8B-aligned)
__device__ __forceinline__ bf16x8 ld8_pair(const ushort_t* p) {
    bf16x4 lo = *(const bf16x4*)p;
    bf16x4 hi = *(const bf16x4*)(p + 4);
    return __builtin_shufflevector(lo, hi, 0, 1, 2, 3, 4, 5, 6, 7);
}

#define MEMFENCE asm volatile("" ::: "memory")
#define BAR      do { MEMFENCE; __builtin_amdgcn_s_barrier(); MEMFENCE; } while (0)

// ================= setup (unchanged from R12) =========
__global__ __launch_bounds__(256) void setup_kernel(
    const int* __restrict__ inputs, const int* __restrict__ p1, const int* __restrict__ p2,
    const float* __restrict__ emb, const float* __restrict__ pos1, const float* __restrict__ pos2,
    const float* __restrict__ w3, const float* __restrict__ w4, const float* __restrict__ w5,
    ushort_t* __restrict__ we_flat, ushort_t* __restrict__ posflat,
    ushort_t* __restrict__ wfw, ushort_t* __restrict__ wfp, ushort_t* __restrict__ corrw)
{
    int bid = blockIdx.x, t = threadIdx.x;

    if (bid < WEB) {                                  // ---- we_flat
        int b = bid / 35, rb = bid - b * 35;
        int r = rb * 4 + (t >> 6), c8 = t & 63;
        if (c8 >= 38) return;
        int e0 = c8 * 8;
        int n = (e0 + 8 <= 300) ? 8 : 300 - e0;
        int flat = r * 300 + e0;
        ushort_t* dst = we_flat + (size_t)b * WE_STRIDE + flat;
        if (r < 130) {
            int tok = (r == 0 || r == 129) ? 0 : inputs[b * L_ + r - 1];
            const float* er = emb + (size_t)tok * 300 + e0;
            short4v v0, v1;
#pragma unroll
            for (int m = 0; m < 4; ++m) v0[m] = (short)f2bf(er[m]);
            *(short4v*)dst = v0;
            if (n == 8) {
#pragma unroll
                for (int m = 0; m < 4; ++m) v1[m] = (short)f2bf(er[4 + m]);
                *(short4v*)(dst + 4) = v1;
            }
        } else {
            short4v z = {0, 0, 0, 0};
            if (flat + 4 <= WE_STRIDE) *(short4v*)dst = z;
            if (n == 8 && flat + 8 <= WE_STRIDE) *(short4v*)(dst + 4) = z;
        }
        return;
    }
    bid -= WEB;
    if (bid < POSB) {                                 // ---- posflat
        int b = bid / 17, rb = bid - b * 17;
        int r = rb * 8 + (t >> 5), c = t & 31;
        if (c >= 25) return;
        int e0 = c * 4;
        int flat = r * 100 + e0;
        ushort_t* dst = posflat + (size_t)b * POS_STRIDE + flat;
        short4v v;
        if (r < 128) {
            int pp1 = p1[b * L_ + r], pp2 = p2[b * L_ + r];
#pragma unroll
            for (int m = 0; m < 4; ++m) {
                int d = e0 + m;
                float x = (d < 50) ? pos1[(size_t)pp1 * 50 + d]
                                   : pos2[(size_t)pp2 * 50 + (d - 50)];
                v[m] = (short)f2bf(x);
            }
            *(short4v*)dst = v;
        } else {
            short4v z = {0, 0, 0, 0};
            if (flat + 4 <= POS_STRIDE) *(short4v*)dst = z;
        }
        return;
    }
    bid -= POSB;
    if (bid < WFWB) {                                 // ---- folded word weights
        int e = (bid * 256 + t) * 8;
        int conv, k;
        const float* w;
        int seg = e;
        if (seg < FN_ * KW0)                { conv = 0; k = 3; w = w3; }
        else if ((seg -= FN_ * KW0) < FN_ * KW1) { conv = 1; k = 4; w = w4; }
        else                                { seg -= FN_ * KW1; conv = 2; k = 5; w = w5; }
        int f, kk0;
        if (conv == 0) { f = seg / KW0; kk0 = seg - f * KW0; }
        else if (conv == 1) { f = seg / KW1; kk0 = seg - f * KW1; }
        else { f = seg / KW2; kk0 = seg - f * KW2; }
        bf16x8 v;
#pragma unroll
        for (int m = 0; m < 8; ++m) {
            int kk = kk0 + m;
            float s = 0.f;
            if (kk < (k + 2) * 300) {
                int mr = kk / 300, c = kk - mr * 300;
                int jlo = (mr - 2 < 0) ? 0 : mr - 2;
                int jhi = (mr < k - 1) ? mr : k - 1;
                for (int j = jlo; j <= jhi; ++j)
                    s += w[(size_t)f * (k * 1000) + j * 1000 + (mr - j) * 300 + c];
            }
            v[m] = (short)f2bf(s);
        }
        *(bf16x8*)(wfw + e) = v;
        return;
    }
    bid -= WFWB;
    if (bid < WFPB) {                                 // ---- pos weights
        int e = (bid * 256 + t) * 8;
        int conv, k;
        const float* w;
        int seg = e;
        if (seg < FN_ * KP0)                { conv = 0; k = 3; w = w3; }
        else if ((seg -= FN_ * KP0) < FN_ * KP1) { conv = 1; k = 4; w = w4; }
        else                                { seg -= FN_ * KP1; conv = 2; k = 5; w = w5; }
        int f, kk0;
        if (conv == 0) { f = seg / KP0; kk0 = seg - f * KP0; }
        else if (conv == 1) { f = seg / KP1; kk0 = seg - f * KP1; }
        else { f = seg / KP2; kk0 = seg - f * KP2; }
        bf16x8 v;
#pragma unroll
        for (int m = 0; m < 8; ++m) {
            int kk = kk0 + m;
            float x = 0.f;
            if (kk < k * 100) {
                int j = kk / 100, c = kk - j * 100;
                x = w[(size_t)f * (k * 1000) + j * 1000 + 900 + c];
            }
            v[m] = (short)f2bf(x);
        }
        *(bf16x8*)(wfp + e) = v;
        return;
    }
    bid -= WFPB;
    {                                                 // ---- corr weights w[f,0,0:900]
        int e = (bid * 256 + t) * 8;
        int conv = e / (FN_ * KC), seg = e - conv * (FN_ * KC);
        int k = 3 + conv;
        const float* w = (conv == 0) ? w3 : (conv == 1) ? w4 : w5;
        int f = seg / KC, kk0 = seg - f * KC;
        bf16x8 v;
#pragma unroll
        for (int m = 0; m < 8; ++m) {
            int kk = kk0 + m;
            v[m] = (kk < 900) ? (short)f2bf(w[(size_t)f * (k * 1000) + kk]) : (short)0;
        }
        *(bf16x8*)(corrw + e) = v;
    }
}

// ===== corr mini-GEMM, regridded for parallelism: 48 blocks x 16 cols.
// corr_all[b, F] = dot(we_flat[b][0:960], corrw[F][0:960]); M=128, per-block N=16.
// 4 waves each own 32 b-rows (acc[2][1]).
__global__ __launch_bounds__(256) void corr_gemm(
    const ushort_t* __restrict__ we_flat, const ushort_t* __restrict__ corrw,
    float* __restrict__ corr_all)
{
    int y = blockIdx.x;                   // 0..47 -> 16-col group
    int t = threadIdx.x;
    int w = t >> 6, lane = t & 63;
    int l15 = lane & 15, lhi = lane >> 4;

    f32x4 acc[2] = {};
    const ushort_t* Bbase = corrw + (size_t)(y << 4) * KC;

    for (int kt = 0; kt < KC / 64; ++kt) {
#pragma unroll
        for (int ks = 0; ks < 2; ++ks) {
            int kk = (kt << 6) + (ks << 5) + (lhi << 3);
            bf16x8 afr[2], bfr;
#pragma unroll
            for (int mf = 0; mf < 2; ++mf) {
                int row = (w << 5) + (mf << 4) + l15;       // b index
                afr[mf] = ld8_pair(we_flat + (size_t)row * WE_STRIDE + kk);
            }
            bfr = *(const bf16x8*)(Bbase + (size_t)l15 * KC + kk);
#pragma unroll
            for (int mf = 0; mf < 2; ++mf)
                acc[mf] = __builtin_amdgcn_mfma_f32_16x16x32_bf16(
                    afr[mf], bfr, acc[mf], 0, 0, 0);
        }
    }
#pragma unroll
    for (int mf = 0; mf < 2; ++mf)
#pragma unroll
        for (int j = 0; j < 4; ++j) {
            int b   = (w << 5) + (mf << 4) + (lhi << 2) + j;
            int col = (y << 4) + l15;
            corr_all[(size_t)b * 768 + col] = acc[mf][j];
        }
}

// ===== conv: grid (b, conv, nhalf), 512 threads (8 waves 2m x 4n, wave 64x32).
// Same 3-buffer single-barrier pipeline as R12; vmcnt re-audited for new counts:
// STAGEB = 2 ops/thread, LOADA = 16 -> steady wait vmcnt(18), tail vmcnt(16).
__global__ __launch_bounds__(512, 4) void conv_fold(
    const ushort_t* __restrict__ we_flat, const ushort_t* __restrict__ posflat,
    const ushort_t* __restrict__ wfw, const ushort_t* __restrict__ wfp,
    const float* __restrict__ corr_all,
    const float* __restrict__ cb3, const float* __restrict__ cb4, const float* __restrict__ cb5,
    float* __restrict__ sf)
{
    __shared__ ushort_t sB[3][8192];          // 3 x 16 KB (chunk-swizzled)
    __shared__ float red[2][128];

    int b    = blockIdx.x;
    int conv = 2 - blockIdx.y;                // longest conv groups first
    int n0c  = blockIdx.z << 7;

    const int ntw = (conv == 0) ? KW0 / 64 : (conv == 1) ? KW1 / 64 : KW2 / 64;
    const int ntp = (conv == 0) ? KP0 / 64 : (conv == 1) ? KP1 / 64 : KP2 / 64;
    const int nt  = ntw + ntp;
    const size_t kwB = (size_t)(ntw * 64) * 2;
    const size_t kpB = (size_t)(ntp * 64) * 2;
    const size_t wfwoff = (conv == 0) ? 0 : (conv == 1) ? (size_t)FN_ * KW0 : (size_t)FN_ * (KW0 + KW1);
    const size_t wfpoff = (conv == 0) ? 0 : (conv == 1) ? (size_t)FN_ * KP0 : (size_t)FN_ * (KP0 + KP1);
    const char* Bw = (const char*)(wfw + wfwoff + (size_t)n0c * (ntw * 64));
    const char* Bp = (const char*)(wfp + wfpoff + (size_t)n0c * (ntp * 64));
    const float* bias = ((conv == 0) ? cb3 : (conv == 1) ? cb4 : cb5) + n0c;
    const int M = 126 - conv;

    int t = threadIdx.x;
    int w = t >> 6, lane = t & 63;
    int wm = w & 1, wn = w >> 1;              // 2 m-halves x 4 n-quarters
    int l15 = lane & 15, lhi = lane >> 4;

    const ushort_t* rowW[4];
    const ushort_t* rowP[4];
#pragma unroll
    for (int mf = 0; mf < 4; ++mf) {
        int row = (wm << 6) + (mf << 4) + l15;
        rowW[mf] = we_flat + (size_t)b * WE_STRIDE  + row * 300;
        rowP[mf] = posflat + (size_t)b * POS_STRIDE + row * 100;
    }

#define STAGEB(BUF, T)                                                          \
    {                                                                           \
        int isw_ = (T) < ntw;                                                   \
        const char* base_ = isw_ ? Bw : Bp;                                     \
        size_t str_ = isw_ ? kwB : kpB;                                         \
        size_t kb_ = (size_t)(isw_ ? (T) : (T) - ntw) << 7;                     \
        _Pragma("unroll")                                                       \
        for (int u = 0; u < 2; ++u) {                                           \
            int ci = (u << 9) + t;                                              \
            int fr = ci >> 3, cin = ci & 7;                                     \
            int sc = cin ^ (fr & 7);                                            \
            gld_lds16(base_ + (size_t)fr * str_ + kb_ + ((size_t)sc << 4),      \
                      (char*)sB + (size_t)(BUF) * 16384 + (ci << 4));           \
        }                                                                       \
    }

#define LOADA(T)                                                                \
    {                                                                           \
        int isw_ = (T) < ntw;                                                   \
        int kb_ = (isw_ ? (T) : (T) - ntw) << 6;                                \
        _Pragma("unroll")                                                       \
        for (int ks = 0; ks < 2; ++ks) {                                        \
            int kk = kb_ + (ks << 5) + (lhi << 3);                              \
            _Pragma("unroll")                                                   \
            for (int mf = 0; mf < 4; ++mf)                                      \
                afr[ks][mf] = ld8_pair((isw_ ? rowW[mf] : rowP[mf]) + kk);      \
        }                                                                       \
    }

    f32x4 acc[4][2] = {};
    bf16x8 afr[2][4];

    // prologue queue: [stage0:2][stage1:2][A(0):16]
    STAGEB(0, 0);
    STAGEB(1, 1);
    LOADA(0);

    for (int kt = 0; kt < nt; ++kt) {
        // steady entry queue: [stage(T):2][A(T):16][stage(T+1):2] -> wait stage(T)
        if (kt == nt - 1) { asm volatile("s_waitcnt vmcnt(16)" ::: "memory"); }
        else              { asm volatile("s_waitcnt vmcnt(18)" ::: "memory"); }
        BAR;

        const ushort_t* cB = &sB[kt % 3][0];
#pragma unroll
        for (int ks = 0; ks < 2; ++ks) {
            bf16x8 bfr[2];
#pragma unroll
            for (int nf = 0; nf < 2; ++nf) {
                int fr = (wn << 5) + (nf << 4) + l15;
                int pc = ((ks << 2) + lhi) ^ (fr & 7);
                bfr[nf] = *(const bf16x8*)&cB[fr * 64 + pc * 8];
            }
            __builtin_amdgcn_s_setprio(1);
#pragma unroll
            for (int mf = 0; mf < 4; ++mf)
#pragma unroll
                for (int nf = 0; nf < 2; ++nf)
                    acc[mf][nf] = __builtin_amdgcn_mfma_f32_16x16x32_bf16(
                        afr[ks][mf], bfr[nf], acc[mf][nf], 0, 0, 0);
            __builtin_amdgcn_s_setprio(0);
        }
        // prefetch next A into the SAME regs (post-consume), then stage T+2
        if (kt + 1 < nt) LOADA(kt + 1);
        if (kt + 2 < nt) STAGEB((kt + 2) % 3, kt + 2);
    }
#undef LOADA
#undef STAGEB

    // ---- epilogue: row-0 corr subtract, masked max, bias+tanh ----
#pragma unroll
    for (int nf = 0; nf < 2; ++nf) {
        int col = (wn << 5) + (nf << 4) + l15;
        float bmax = -INFINITY;
#pragma unroll
        for (int mf = 0; mf < 4; ++mf) {
#pragma unroll
            for (int j = 0; j < 4; ++j) {
                int i = (wm << 6) + (mf << 4) + (lhi << 2) + j;
                float v = acc[mf][nf][j];
                if (i == 0) v -= corr_all[(size_t)b * 768 + (conv << 8) + n0c + col];
                if (i < M) bmax = fmaxf(bmax, v);
            }
        }
        bmax = fmaxf(bmax, __shfl_xor(bmax, 16));
        bmax = fmaxf(bmax, __shfl_xor(bmax, 32));
        if (lane < 16) red[wm][col] = bmax;
    }
    __syncthreads();
    if (t < 128) {
        float m = fmaxf(red[0][t], red[1][t]);
        sf[(size_t)b * (3 * FN_) + (conv << 8) + n0c + t] = tanhf(m + bias[t]);
    }
}

// ---- tail: span/lex feats + g + final logits, one block per b ----
__device__ __forceinline__ int tok_at(const int* inputs, int b, int idx) {
    return (idx >= 0 && idx < L_) ? inputs[b * L_ + idx] : 0;
}
__global__ __launch_bounds__(256) void tail_kernel(
    const int* __restrict__ inputs,
    const int* __restrict__ e1s, const int* __restrict__ e1e,
    const int* __restrict__ e2s, const int* __restrict__ e2e,
    const float* __restrict__ emb, const float* __restrict__ sf,
    const float* __restrict__ W1, const float* __restrict__ b1,
    const float* __restrict__ W2, const float* __restrict__ b2,
    float* __restrict__ y)
{
    __shared__ float o_loc[1900];
    __shared__ float sfl[3 * FN_];

    int b = blockIdx.x, t = threadIdx.x;
    int lane = t & 63, w = t >> 6;

    for (int k = t; k < 3 * FN_; k += 256) sfl[k] = sf[(size_t)b * (3 * FN_) + k];

    int s1 = e1s[b], t1 = e1e[b], s2 = e2s[b], t2 = e2e[b];
    float inv1 = 1.f / (float)(t1 - s1 + 1);
    float inv2 = 1.f / (float)(t2 - s2 + 1);
    int ta = tok_at(inputs, b, s1 - 1), tb = tok_at(inputs, b, t1 + 1);
    int tc = tok_at(inputs, b, s2 - 1), td = tok_at(inputs, b, t2 + 1);
    for (int d = t; d < E_; d += 256) {
        float s = 0.f;
        for (int p = s1; p <= t1; ++p) s += emb[(size_t)tok_at(inputs, b, p) * E_ + d];
        o_loc[d] = s * inv1;
        s = 0.f;
        for (int p = s2; p <= t2; ++p) s += emb[(size_t)tok_at(inputs, b, p) * E_ + d];
        o_loc[E_ + d] = s * inv2;
        o_loc[2 * E_ + d] = emb[(size_t)ta * E_ + d];
        o_loc[3 * E_ + d] = emb[(size_t)tb * E_ + d];
        o_loc[4 * E_ + d] = emb[(size_t)tc * E_ + d];
        o_loc[5 * E_ + d] = emb[(size_t)td * E_ + d];
    }
    __syncthreads();

    for (int h = w; h < H2_; h += 4) {
        const float* wr = W1 + (size_t)h * (3 * FN_);
        float acc = 0.f;
#pragma unroll
        for (int j = 0; j < 12; ++j) acc += sfl[lane + (j << 6)] * wr[lane + (j << 6)];
        for (int off = 32; off; off >>= 1) acc += __shfl_down(acc, off);
        if (lane == 0) o_loc[1800 + h] = tanhf(acc + b1[h]);
    }
    __syncthreads();

    for (int lab = w; lab < LAB_; lab += 4) {
        const float* wr = W2 + (size_t)lab * 1900;
        float acc = 0.f;
        for (int d = lane; d < 1900; d += 64) acc += o_loc[d] * wr[d];
        for (int off = 32; off; off >>= 1) acc += __shfl_down(acc, off);
        if (lane == 0) y[(size_t)b * LAB_ + lab] = acc + b2[lab];
    }
}

extern "C" void kernel_launch(void* const* d_in, const int* in_sizes, int n_in,
                              void* d_out, int out_size, void* d_ws, size_t ws_size,
                              hipStream_t stream) {
    const int*   inputs = (const int*)d_in[0];
    const int*   e1s    = (const int*)d_in[1];
    const int*   e1e    = (const int*)d_in[2];
    const int*   e2s    = (const int*)d_in[3];
    const int*   e2e    = (const int*)d_in[4];
    const int*   p1     = (const int*)d_in[5];
    const int*   p2     = (const int*)d_in[6];
    const float* emb    = (const float*)d_in[7];
    const float* pos1   = (const float*)d_in[8];
    const float* pos2   = (const float*)d_in[9];
    const float* w3     = (const float*)d_in[10];
    const float* cb3    = (const float*)d_in[11];
    const float* w4     = (const float*)d_in[12];
    const float* cb4    = (const float*)d_in[13];
    const float* w5     = (const float*)d_in[14];
    const float* cb5    = (const float*)d_in[15];
    const float* W1     = (const float*)d_in[16];
    const float* b1     = (const float*)d_in[17];
    const float* W2     = (const float*)d_in[18];
    const float* b2     = (const float*)d_in[19];
    float* y = (float*)d_out;

    char* ws = (char*)d_ws;
    size_t off = 0;
    ushort_t* we_flat = (ushort_t*)(ws + off); off += (size_t)N_WE * 2;
    ushort_t* posflat = (ushort_t*)(ws + off); off += (size_t)N_POS * 2;
    ushort_t* wfw     = (ushort_t*)(ws + off); off += (size_t)N_WFW * 2;
    ushort_t* wfp     = (ushort_t*)(ws + off); off += (size_t)N_WFP * 2;
    ushort_t* corrw   = (ushort_t*)(ws + off); off += (size_t)N_CORR * 2;
    float*    corr_all= (float*)(ws + off);    off += (size_t)B_ * 768 * 4;
    float*    sf      = (float*)(ws + off);    off += (size_t)B_ * 3 * FN_ * 4;

    setup_kernel<<<dim3(SETUP_BLOCKS), dim3(256), 0, stream>>>(
        inputs, p1, p2, emb, pos1, pos2, w3, w4, w5,
        we_flat, posflat, wfw, wfp, corrw);

    corr_gemm<<<dim3(48), dim3(256), 0, stream>>>(we_flat, corrw, corr_all);

    conv_fold<<<dim3(B_, 3, 2), dim3(512), 0, stream>>>(
        we_flat, posflat, wfw, wfp, corr_all, cb3, cb4, cb5, sf);

    tail_kernel<<<dim3(B_), dim3(256), 0, stream>>>(
        inputs, e1s, e1e, e2s, e2e, emb, sf, W1, b1, W2, b2, y);
}

// Round 14
// 181.015 us; speedup vs baseline: 1.2795x; 1.2795x over previous
//
#include <hip/hip_runtime.h>
#include <math.h>

#define B_   128
#define L_   128
#define E_   300
#define P_   50
#define FN_  256
#define H2_  100
#define LAB_ 19

typedef unsigned short ushort_t;
typedef __attribute__((ext_vector_type(8))) short bf16x8;
typedef __attribute__((ext_vector_type(4))) short bf16x4;
typedef __attribute__((ext_vector_type(4))) short short4v;
typedef __attribute__((ext_vector_type(4))) float f32x4;

// folded-K geometry (stride-300/100): word K=(k+2)*300 pad64, pos K=k*100 pad64
#define KW0 1536
#define KW1 1856
#define KW2 2112
#define KP0 320
#define KP1 448
#define KP2 512
#define KC  960

#define WE_STRIDE  40960   // per-b we_flat elems (130x300 + zero tail)
#define POS_STRIDE 13312   // per-b posflat elems (128x100 + zero tail)

#define N_WE   (B_ * WE_STRIDE)
#define N_POS  (B_ * POS_STRIDE)
#define N_WFW  (FN_ * (KW0 + KW1 + KW2))
#define N_WFP  (FN_ * (KP0 + KP1 + KP2))
#define N_CORR (3 * FN_ * KC)

#define WEB  (B_ * 35)
#define POSB (B_ * 17)
#define WFWB (N_WFW / 2048)
#define WFPB (N_WFP / 2048)
#define CORB (N_CORR / 2048)
#define SETUP_BLOCKS (WEB + POSB + WFWB + WFPB + CORB)

__device__ __forceinline__ ushort_t f2bf(float x) {
    unsigned u = __float_as_uint(x);
    u += 0x7FFFu + ((u >> 16) & 1u);
    return (ushort_t)(u >> 16);
}

__device__ __forceinline__ void gld_lds16(const void* g, void* lds_uniform) {
    __builtin_amdgcn_global_load_lds(
        (const __attribute__((address_space(1))) void*)g,
        (__attribute__((address_space(3))) void*)lds_uniform,
        16, 0, 0);
}

// 8 bf16 via two 8B loads (rows stride 600/200B: only 8B-aligned)
__device__ __forceinline__ bf16x8 ld8_pair(const ushort_t* p) {
    bf16x4 lo = *(const bf16x4*)p;
    bf16x4 hi = *(const bf16x4*)(p + 4);
    return __builtin_shufflevector(lo, hi, 0, 1, 2, 3, 4, 5, 6, 7);
}

#define MEMFENCE asm volatile("" ::: "memory")
#define BAR      do { MEMFENCE; __builtin_amdgcn_s_barrier(); MEMFENCE; } while (0)

// ================= setup (unchanged) =========
__global__ __launch_bounds__(256) void setup_kernel(
    const int* __restrict__ inputs, const int* __restrict__ p1, const int* __restrict__ p2,
    const float* __restrict__ emb, const float* __restrict__ pos1, const float* __restrict__ pos2,
    const float* __restrict__ w3, const float* __restrict__ w4, const float* __restrict__ w5,
    ushort_t* __restrict__ we_flat, ushort_t* __restrict__ posflat,
    ushort_t* __restrict__ wfw, ushort_t* __restrict__ wfp, ushort_t* __restrict__ corrw)
{
    int bid = blockIdx.x, t = threadIdx.x;

    if (bid < WEB) {                                  // ---- we_flat
        int b = bid / 35, rb = bid - b * 35;
        int r = rb * 4 + (t >> 6), c8 = t & 63;
        if (c8 >= 38) return;
        int e0 = c8 * 8;
        int n = (e0 + 8 <= 300) ? 8 : 300 - e0;
        int flat = r * 300 + e0;
        ushort_t* dst = we_flat + (size_t)b * WE_STRIDE + flat;
        if (r < 130) {
            int tok = (r == 0 || r == 129) ? 0 : inputs[b * L_ + r - 1];
            const float* er = emb + (size_t)tok * 300 + e0;
            short4v v0, v1;
#pragma unroll
            for (int m = 0; m < 4; ++m) v0[m] = (short)f2bf(er[m]);
            *(short4v*)dst = v0;
            if (n == 8) {
#pragma unroll
                for (int m = 0; m < 4; ++m) v1[m] = (short)f2bf(er[4 + m]);
                *(short4v*)(dst + 4) = v1;
            }
        } else {
            short4v z = {0, 0, 0, 0};
            if (flat + 4 <= WE_STRIDE) *(short4v*)dst = z;
            if (n == 8 && flat + 8 <= WE_STRIDE) *(short4v*)(dst + 4) = z;
        }
        return;
    }
    bid -= WEB;
    if (bid < POSB) {                                 // ---- posflat
        int b = bid / 17, rb = bid - b * 17;
        int r = rb * 8 + (t >> 5), c = t & 31;
        if (c >= 25) return;
        int e0 = c * 4;
        int flat = r * 100 + e0;
        ushort_t* dst = posflat + (size_t)b * POS_STRIDE + flat;
        short4v v;
        if (r < 128) {
            int pp1 = p1[b * L_ + r], pp2 = p2[b * L_ + r];
#pragma unroll
            for (int m = 0; m < 4; ++m) {
                int d = e0 + m;
                float x = (d < 50) ? pos1[(size_t)pp1 * 50 + d]
                                   : pos2[(size_t)pp2 * 50 + (d - 50)];
                v[m] = (short)f2bf(x);
            }
            *(short4v*)dst = v;
        } else {
            short4v z = {0, 0, 0, 0};
            if (flat + 4 <= POS_STRIDE) *(short4v*)dst = z;
        }
        return;
    }
    bid -= POSB;
    if (bid < WFWB) {                                 // ---- folded word weights
        int e = (bid * 256 + t) * 8;
        int conv, k;
        const float* w;
        int seg = e;
        if (seg < FN_ * KW0)                { conv = 0; k = 3; w = w3; }
        else if ((seg -= FN_ * KW0) < FN_ * KW1) { conv = 1; k = 4; w = w4; }
        else                                { seg -= FN_ * KW1; conv = 2; k = 5; w = w5; }
        int f, kk0;
        if (conv == 0) { f = seg / KW0; kk0 = seg - f * KW0; }
        else if (conv == 1) { f = seg / KW1; kk0 = seg - f * KW1; }
        else { f = seg / KW2; kk0 = seg - f * KW2; }
        bf16x8 v;
#pragma unroll
        for (int m = 0; m < 8; ++m) {
            int kk = kk0 + m;
            float s = 0.f;
            if (kk < (k + 2) * 300) {
                int mr = kk / 300, c = kk - mr * 300;
                int jlo = (mr - 2 < 0) ? 0 : mr - 2;
                int jhi = (mr < k - 1) ? mr : k - 1;
                for (int j = jlo; j <= jhi; ++j)
                    s += w[(size_t)f * (k * 1000) + j * 1000 + (mr - j) * 300 + c];
            }
            v[m] = (short)f2bf(s);
        }
        *(bf16x8*)(wfw + e) = v;
        return;
    }
    bid -= WFWB;
    if (bid < WFPB) {                                 // ---- pos weights
        int e = (bid * 256 + t) * 8;
        int conv, k;
        const float* w;
        int seg = e;
        if (seg < FN_ * KP0)                { conv = 0; k = 3; w = w3; }
        else if ((seg -= FN_ * KP0) < FN_ * KP1) { conv = 1; k = 4; w = w4; }
        else                                { seg -= FN_ * KP1; conv = 2; k = 5; w = w5; }
        int f, kk0;
        if (conv == 0) { f = seg / KP0; kk0 = seg - f * KP0; }
        else if (conv == 1) { f = seg / KP1; kk0 = seg - f * KP1; }
        else { f = seg / KP2; kk0 = seg - f * KP2; }
        bf16x8 v;
#pragma unroll
        for (int m = 0; m < 8; ++m) {
            int kk = kk0 + m;
            float x = 0.f;
            if (kk < k * 100) {
                int j = kk / 100, c = kk - j * 100;
                x = w[(size_t)f * (k * 1000) + j * 1000 + 900 + c];
            }
            v[m] = (short)f2bf(x);
        }
        *(bf16x8*)(wfp + e) = v;
        return;
    }
    bid -= WFPB;
    {                                                 // ---- corr weights w[f,0,0:900]
        int e = (bid * 256 + t) * 8;
        int conv = e / (FN_ * KC), seg = e - conv * (FN_ * KC);
        int k = 3 + conv;
        const float* w = (conv == 0) ? w3 : (conv == 1) ? w4 : w5;
        int f = seg / KC, kk0 = seg - f * KC;
        bf16x8 v;
#pragma unroll
        for (int m = 0; m < 8; ++m) {
            int kk = kk0 + m;
            v[m] = (kk < 900) ? (short)f2bf(w[(size_t)f * (k * 1000) + kk]) : (short)0;
        }
        *(bf16x8*)(corrw + e) = v;
    }
}

// ===== corr mini-GEMM (R13's 48-block version): 16 filter-cols per block =====
__global__ __launch_bounds__(256) void corr_gemm(
    const ushort_t* __restrict__ we_flat, const ushort_t* __restrict__ corrw,
    float* __restrict__ corr_all)
{
    int y = blockIdx.x;                   // 0..47 -> 16-col group
    int t = threadIdx.x;
    int w = t >> 6, lane = t & 63;
    int l15 = lane & 15, lhi = lane >> 4;

    f32x4 acc[2] = {};
    const ushort_t* Bbase = corrw + (size_t)(y << 4) * KC;

    for (int kt = 0; kt < KC / 64; ++kt) {
#pragma unroll
        for (int ks = 0; ks < 2; ++ks) {
            int kk = (kt << 6) + (ks << 5) + (lhi << 3);
            bf16x8 afr[2], bfr;
#pragma unroll
            for (int mf = 0; mf < 2; ++mf) {
                int row = (w << 5) + (mf << 4) + l15;       // b index
                afr[mf] = ld8_pair(we_flat + (size_t)row * WE_STRIDE + kk);
            }
            bfr = *(const bf16x8*)(Bbase + (size_t)l15 * KC + kk);
#pragma unroll
            for (int mf = 0; mf < 2; ++mf)
                acc[mf] = __builtin_amdgcn_mfma_f32_16x16x32_bf16(
                    afr[mf], bfr, acc[mf], 0, 0, 0);
        }
    }
#pragma unroll
    for (int mf = 0; mf < 2; ++mf)
#pragma unroll
        for (int j = 0; j < 4; ++j) {
            int b   = (w << 5) + (mf << 4) + (lhi << 2) + j;
            int col = (y << 4) + l15;
            corr_all[(size_t)b * 768 + col] = acc[mf][j];
        }
}

// ===== conv (EXACT R12: 256 thr, 2m x 2n wave 64x64, 3-buf single-barrier,
// in-order-audited vmcnt, single A-frag buffer reloaded post-consume) =====
__global__ __launch_bounds__(256, 3) void conv_fold(
    const ushort_t* __restrict__ we_flat, const ushort_t* __restrict__ posflat,
    const ushort_t* __restrict__ wfw, const ushort_t* __restrict__ wfp,
    const float* __restrict__ corr_all,
    const float* __restrict__ cb3, const float* __restrict__ cb4, const float* __restrict__ cb5,
    float* __restrict__ sf)
{
    __shared__ ushort_t sB[3][8192];          // 3 x 16 KB (chunk-swizzled)
    __shared__ float red[2][128];

    int b    = blockIdx.x;
    int conv = 2 - blockIdx.y;                // longest conv groups first
    int n0c  = blockIdx.z << 7;

    const int ntw = (conv == 0) ? KW0 / 64 : (conv == 1) ? KW1 / 64 : KW2 / 64;
    const int ntp = (conv == 0) ? KP0 / 64 : (conv == 1) ? KP1 / 64 : KP2 / 64;
    const int nt  = ntw + ntp;
    const size_t kwB = (size_t)(ntw * 64) * 2;
    const size_t kpB = (size_t)(ntp * 64) * 2;
    const size_t wfwoff = (conv == 0) ? 0 : (conv == 1) ? (size_t)FN_ * KW0 : (size_t)FN_ * (KW0 + KW1);
    const size_t wfpoff = (conv == 0) ? 0 : (conv == 1) ? (size_t)FN_ * KP0 : (size_t)FN_ * (KP0 + KP1);
    const char* Bw = (const char*)(wfw + wfwoff + (size_t)n0c * (ntw * 64));
    const char* Bp = (const char*)(wfp + wfpoff + (size_t)n0c * (ntp * 64));
    const float* bias = ((conv == 0) ? cb3 : (conv == 1) ? cb4 : cb5) + n0c;
    const int M = 126 - conv;

    int t = threadIdx.x;
    int w = t >> 6, lane = t & 63;
    int wm = w & 1, wn = w >> 1;
    int l15 = lane & 15, lhi = lane >> 4;

    const ushort_t* rowW[4];
    const ushort_t* rowP[4];
#pragma unroll
    for (int mf = 0; mf < 4; ++mf) {
        int row = (wm << 6) + (mf << 4) + l15;
        rowW[mf] = we_flat + (size_t)b * WE_STRIDE  + row * 300;
        rowP[mf] = posflat + (size_t)b * POS_STRIDE + row * 100;
    }

#define STAGEB(BUF, T)                                                          \
    {                                                                           \
        int isw_ = (T) < ntw;                                                   \
        const char* base_ = isw_ ? Bw : Bp;                                     \
        size_t str_ = isw_ ? kwB : kpB;                                         \
        size_t kb_ = (size_t)(isw_ ? (T) : (T) - ntw) << 7;                     \
        _Pragma("unroll")                                                       \
        for (int u = 0; u < 4; ++u) {                                           \
            int ci = (u << 8) + t;                                              \
            int fr = ci >> 3, cin = ci & 7;                                     \
            int sc = cin ^ (fr & 7);                                            \
            gld_lds16(base_ + (size_t)fr * str_ + kb_ + ((size_t)sc << 4),      \
                      (char*)sB + (size_t)(BUF) * 16384 + (ci << 4));           \
        }                                                                       \
    }

#define LOADA(T)                                                                \
    {                                                                           \
        int isw_ = (T) < ntw;                                                   \
        int kb_ = (isw_ ? (T) : (T) - ntw) << 6;                                \
        _Pragma("unroll")                                                       \
        for (int ks = 0; ks < 2; ++ks) {                                        \
            int kk = kb_ + (ks << 5) + (lhi << 3);                              \
            _Pragma("unroll")                                                   \
            for (int mf = 0; mf < 4; ++mf)                                      \
                afr[ks][mf] = ld8_pair((isw_ ? rowW[mf] : rowP[mf]) + kk);      \
        }                                                                       \
    }

    f32x4 acc[4][4] = {};
    bf16x8 afr[2][4];

    // prologue: queue = [stage0:4][stage1:4][A(0):16]
    STAGEB(0, 0);
    STAGEB(1, 1);
    LOADA(0);

    for (int kt = 0; kt < nt; ++kt) {
        // entry queue (steady): [stage(T):4][A(T):16][stage(T+1):4]
        if (kt == nt - 1) { asm volatile("s_waitcnt vmcnt(16)" ::: "memory"); }
        else              { asm volatile("s_waitcnt vmcnt(20)" ::: "memory"); }
        BAR;

        const ushort_t* cB = &sB[kt % 3][0];
#pragma unroll
        for (int ks = 0; ks < 2; ++ks) {
            bf16x8 bfr[4];
#pragma unroll
            for (int nf = 0; nf < 4; ++nf) {
                int fr = (wn << 6) + (nf << 4) + l15;
                int pc = ((ks << 2) + lhi) ^ (fr & 7);
                bfr[nf] = *(const bf16x8*)&cB[fr * 64 + pc * 8];
            }
            __builtin_amdgcn_s_setprio(1);
#pragma unroll
            for (int mf = 0; mf < 4; ++mf)
#pragma unroll
                for (int nf = 0; nf < 4; ++nf)
                    acc[mf][nf] = __builtin_amdgcn_mfma_f32_16x16x32_bf16(
                        afr[ks][mf], bfr[nf], acc[mf][nf], 0, 0, 0);
            __builtin_amdgcn_s_setprio(0);
        }
        // prefetch next A into the SAME regs (post-consume), then stage T+2
        if (kt + 1 < nt) LOADA(kt + 1);
        if (kt + 2 < nt) STAGEB((kt + 2) % 3, kt + 2);
    }
#undef LOADA
#undef STAGEB

    // ---- epilogue: row-0 corr subtract, masked max, bias+tanh ----
#pragma unroll
    for (int nf = 0; nf < 4; ++nf) {
        int col = (wn << 6) + (nf << 4) + l15;
        float bmax = -INFINITY;
#pragma unroll
        for (int mf = 0; mf < 4; ++mf) {
#pragma unroll
            for (int j = 0; j < 4; ++j) {
                int i = (wm << 6) + (mf << 4) + (lhi << 2) + j;
                float v = acc[mf][nf][j];
                if (i == 0) v -= corr_all[(size_t)b * 768 + (conv << 8) + n0c + col];
                if (i < M) bmax = fmaxf(bmax, v);
            }
        }
        bmax = fmaxf(bmax, __shfl_xor(bmax, 16));
        bmax = fmaxf(bmax, __shfl_xor(bmax, 32));
        if (lane < 16) red[wm][col] = bmax;
    }
    __syncthreads();
    if (t < 128) {
        float m = fmaxf(red[0][t], red[1][t]);
        sf[(size_t)b * (3 * FN_) + (conv << 8) + n0c + t] = tanhf(m + bias[t]);
    }
}

// ---- tail: span/lex feats + g + final logits, one block per b ----
__device__ __forceinline__ int tok_at(const int* inputs, int b, int idx) {
    return (idx >= 0 && idx < L_) ? inputs[b * L_ + idx] : 0;
}
__global__ __launch_bounds__(256) void tail_kernel(
    const int* __restrict__ inputs,
    const int* __restrict__ e1s, const int* __restrict__ e1e,
    const int* __restrict__ e2s, const int* __restrict__ e2e,
    const float* __restrict__ emb, const float* __restrict__ sf,
    const float* __restrict__ W1, const float* __restrict__ b1,
    const float* __restrict__ W2, const float* __restrict__ b2,
    float* __restrict__ y)
{
    __shared__ float o_loc[1900];
    __shared__ float sfl[3 * FN_];

    int b = blockIdx.x, t = threadIdx.x;
    int lane = t & 63, w = t >> 6;

    for (int k = t; k < 3 * FN_; k += 256) sfl[k] = sf[(size_t)b * (3 * FN_) + k];

    int s1 = e1s[b], t1 = e1e[b], s2 = e2s[b], t2 = e2e[b];
    float inv1 = 1.f / (float)(t1 - s1 + 1);
    float inv2 = 1.f / (float)(t2 - s2 + 1);
    int ta = tok_at(inputs, b, s1 - 1), tb = tok_at(inputs, b, t1 + 1);
    int tc = tok_at(inputs, b, s2 - 1), td = tok_at(inputs, b, t2 + 1);
    for (int d = t; d < E_; d += 256) {
        float s = 0.f;
        for (int p = s1; p <= t1; ++p) s += emb[(size_t)tok_at(inputs, b, p) * E_ + d];
        o_loc[d] = s * inv1;
        s = 0.f;
        for (int p = s2; p <= t2; ++p) s += emb[(size_t)tok_at(inputs, b, p) * E_ + d];
        o_loc[E_ + d] = s * inv2;
        o_loc[2 * E_ + d] = emb[(size_t)ta * E_ + d];
        o_loc[3 * E_ + d] = emb[(size_t)tb * E_ + d];
        o_loc[4 * E_ + d] = emb[(size_t)tc * E_ + d];
        o_loc[5 * E_ + d] = emb[(size_t)td * E_ + d];
    }
    __syncthreads();

    for (int h = w; h < H2_; h += 4) {
        const float* wr = W1 + (size_t)h * (3 * FN_);
        float acc = 0.f;
#pragma unroll
        for (int j = 0; j < 12; ++j) acc += sfl[lane + (j << 6)] * wr[lane + (j << 6)];
        for (int off = 32; off; off >>= 1) acc += __shfl_down(acc, off);
        if (lane == 0) o_loc[1800 + h] = tanhf(acc + b1[h]);
    }
    __syncthreads();

    for (int lab = w; lab < LAB_; lab += 4) {
        const float* wr = W2 + (size_t)lab * 1900;
        float acc = 0.f;
        for (int d = lane; d < 1900; d += 64) acc += o_loc[d] * wr[d];
        for (int off = 32; off; off >>= 1) acc += __shfl_down(acc, off);
        if (lane == 0) y[(size_t)b * LAB_ + lab] = acc + b2[lab];
    }
}

extern "C" void kernel_launch(void* const* d_in, const int* in_sizes, int n_in,
                              void* d_out, int out_size, void* d_ws, size_t ws_size,
                              hipStream_t stream) {
    const int*   inputs = (const int*)d_in[0];
    const int*   e1s    = (const int*)d_in[1];
    const int*   e1e    = (const int*)d_in[2];
    const int*   e2s    = (const int*)d_in[3];
    const int*   e2e    = (const int*)d_in[4];
    const int*   p1     = (const int*)d_in[5];
    const int*   p2     = (const int*)d_in[6];
    const float* emb    = (const float*)d_in[7];
    const float* pos1   = (const float*)d_in[8];
    const float* pos2   = (const float*)d_in[9];
    const float* w3     = (const float*)d_in[10];
    const float* cb3    = (const float*)d_in[11];
    const float* w4     = (const float*)d_in[12];
    const float* cb4    = (const float*)d_in[13];
    const float* w5     = (const float*)d_in[14];
    const float* cb5    = (const float*)d_in[15];
    const float* W1     = (const float*)d_in[16];
    const float* b1     = (const float*)d_in[17];
    const float* W2     = (const float*)d_in[18];
    const float* b2     = (const float*)d_in[19];
    float* y = (float*)d_out;

    char* ws = (char*)d_ws;
    size_t off = 0;
    ushort_t* we_flat = (ushort_t*)(ws + off); off += (size_t)N_WE * 2;
    ushort_t* posflat = (ushort_t*)(ws + off); off += (size_t)N_POS * 2;
    ushort_t* wfw     = (ushort_t*)(ws + off); off += (size_t)N_WFW * 2;
    ushort_t* wfp     = (ushort_t*)(ws + off); off += (size_t)N_WFP * 2;
    ushort_t* corrw   = (ushort_t*)(ws + off); off += (size_t)N_CORR * 2;
    float*    corr_all= (float*)(ws + off);    off += (size_t)B_ * 768 * 4;
    float*    sf      = (float*)(ws + off);    off += (size_t)B_ * 3 * FN_ * 4;

    setup_kernel<<<dim3(SETUP_BLOCKS), dim3(256), 0, stream>>>(
        inputs, p1, p2, emb, pos1, pos2, w3, w4, w5,
        we_flat, posflat, wfw, wfp, corrw);

    corr_gemm<<<dim3(48), dim3(256), 0, stream>>>(we_flat, corrw, corr_all);

    conv_fold<<<dim3(B_, 3, 2), dim3(256), 0, stream>>>(
        we_flat, posflat, wfw, wfp, corr_all, cb3, cb4, cb5, sf);

    tail_kernel<<<dim3(B_), dim3(256), 0, stream>>>(
        inputs, e1s, e1e, e2s, e2e, emb, sf, W1, b1, W2, b2, y);
}

// Round 15
// 173.302 us; speedup vs baseline: 1.3364x; 1.0445x over previous
//
#include <hip/hip_runtime.h>
#include <math.h>

#define B_   128
#define L_   128
#define E_   300
#define P_   50
#define FN_  256
#define H2_  100
#define LAB_ 19

typedef unsigned short ushort_t;
typedef __attribute__((ext_vector_type(8))) short bf16x8;
typedef __attribute__((ext_vector_type(4))) short bf16x4;
typedef __attribute__((ext_vector_type(4))) short short4v;
typedef __attribute__((ext_vector_type(4))) float f32x4;

// Unified folded geometry: ALL convs share A (stride-300 word / stride-100 pos).
// Weights zero-padded to uniform K strides: word KWU=2112 (=7*300 pad64),
// pos KPU=512 (=5*100 pad64). corr K=960.
#define KWU 2112
#define KPU 512
#define KC  960
#define NTW 33
#define NTP 8
#define NT  41

#define WE_STRIDE  40960   // per-b we_flat elems (130x300 + zero tail; max read 40211)
#define POS_STRIDE 13312   // per-b posflat elems (128x100 + zero tail; max read 13211)

#define N_WE    (B_ * WE_STRIDE)
#define N_POS   (B_ * POS_STRIDE)
#define N_WFWU  (3 * FN_ * KWU)              // 1,622,016
#define N_WFPU  (3 * FN_ * KPU)              // 393,216
#define N_CORR  (3 * FN_ * KC)               // 737,280

#define WEB   (B_ * 35)
#define POSB  (B_ * 17)
#define WFWB  (N_WFWU / 2048)                // 792
#define WFPB  (N_WFPU / 2048)                // 192
#define CORB  (N_CORR / 2048)                // 360
#define SETUP_BLOCKS (WEB + POSB + WFWB + WFPB + CORB)

__device__ __forceinline__ ushort_t f2bf(float x) {
    unsigned u = __float_as_uint(x);
    u += 0x7FFFu + ((u >> 16) & 1u);
    return (ushort_t)(u >> 16);
}

__device__ __forceinline__ void gld_lds16(const void* g, void* lds_uniform) {
    __builtin_amdgcn_global_load_lds(
        (const __attribute__((address_space(1))) void*)g,
        (__attribute__((address_space(3))) void*)lds_uniform,
        16, 0, 0);
}

// 8 bf16 via two 8B loads (rows stride 600/200B: only 8B-aligned)
__device__ __forceinline__ bf16x8 ld8_pair(const ushort_t* p) {
    bf16x4 lo = *(const bf16x4*)p;
    bf16x4 hi = *(const bf16x4*)(p + 4);
    return __builtin_shufflevector(lo, hi, 0, 1, 2, 3, 4, 5, 6, 7);
}

#define MEMFENCE asm volatile("" ::: "memory")
#define BAR      do { MEMFENCE; __builtin_amdgcn_s_barrier(); MEMFENCE; } while (0)

// ================= setup =========
__global__ __launch_bounds__(256) void setup_kernel(
    const int* __restrict__ inputs, const int* __restrict__ p1, const int* __restrict__ p2,
    const float* __restrict__ emb, const float* __restrict__ pos1, const float* __restrict__ pos2,
    const float* __restrict__ w3, const float* __restrict__ w4, const float* __restrict__ w5,
    ushort_t* __restrict__ we_flat, ushort_t* __restrict__ posflat,
    ushort_t* __restrict__ wfwu, ushort_t* __restrict__ wfpu, ushort_t* __restrict__ corrw)
{
    int bid = blockIdx.x, t = threadIdx.x;

    if (bid < WEB) {                                  // ---- we_flat
        int b = bid / 35, rb = bid - b * 35;
        int r = rb * 4 + (t >> 6), c8 = t & 63;
        if (c8 >= 38) return;
        int e0 = c8 * 8;
        int n = (e0 + 8 <= 300) ? 8 : 300 - e0;
        int flat = r * 300 + e0;
        ushort_t* dst = we_flat + (size_t)b * WE_STRIDE + flat;
        if (r < 130) {
            int tok = (r == 0 || r == 129) ? 0 : inputs[b * L_ + r - 1];
            const float* er = emb + (size_t)tok * 300 + e0;
            short4v v0, v1;
#pragma unroll
            for (int m = 0; m < 4; ++m) v0[m] = (short)f2bf(er[m]);
            *(short4v*)dst = v0;
            if (n == 8) {
#pragma unroll
                for (int m = 0; m < 4; ++m) v1[m] = (short)f2bf(er[4 + m]);
                *(short4v*)(dst + 4) = v1;
            }
        } else {
            short4v z = {0, 0, 0, 0};
            if (flat + 4 <= WE_STRIDE) *(short4v*)dst = z;
            if (n == 8 && flat + 8 <= WE_STRIDE) *(short4v*)(dst + 4) = z;
        }
        return;
    }
    bid -= WEB;
    if (bid < POSB) {                                 // ---- posflat
        int b = bid / 17, rb = bid - b * 17;
        int r = rb * 8 + (t >> 5), c = t & 31;
        if (c >= 25) return;
        int e0 = c * 4;
        int flat = r * 100 + e0;
        ushort_t* dst = posflat + (size_t)b * POS_STRIDE + flat;
        short4v v;
        if (r < 128) {
            int pp1 = p1[b * L_ + r], pp2 = p2[b * L_ + r];
#pragma unroll
            for (int m = 0; m < 4; ++m) {
                int d = e0 + m;
                float x = (d < 50) ? pos1[(size_t)pp1 * 50 + d]
                                   : pos2[(size_t)pp2 * 50 + (d - 50)];
                v[m] = (short)f2bf(x);
            }
            *(short4v*)dst = v;
        } else {
            short4v z = {0, 0, 0, 0};
            if (flat + 4 <= POS_STRIDE) *(short4v*)dst = z;
        }
        return;
    }
    bid -= POSB;
    if (bid < WFWB) {                                 // ---- unified folded word weights
        int e = (bid * 256 + t) * 8;
        int conv = e / (FN_ * KWU);
        int rem  = e - conv * (FN_ * KWU);
        int f = rem / KWU, kk0 = rem - f * KWU;
        int k = 3 + conv;
        const float* w = (conv == 0) ? w3 : (conv == 1) ? w4 : w5;
        bf16x8 v;
#pragma unroll
        for (int m = 0; m < 8; ++m) {
            int kk = kk0 + m;
            float s = 0.f;
            if (kk < (k + 2) * 300) {
                int mr = kk / 300, c = kk - mr * 300;
                int jlo = (mr - 2 < 0) ? 0 : mr - 2;
                int jhi = (mr < k - 1) ? mr : k - 1;
                for (int j = jlo; j <= jhi; ++j)
                    s += w[(size_t)f * (k * 1000) + j * 1000 + (mr - j) * 300 + c];
            }
            v[m] = (short)f2bf(s);
        }
        *(bf16x8*)(wfwu + e) = v;
        return;
    }
    bid -= WFWB;
    if (bid < WFPB) {                                 // ---- unified pos weights
        int e = (bid * 256 + t) * 8;
        int conv = e / (FN_ * KPU);
        int rem  = e - conv * (FN_ * KPU);
        int f = rem / KPU, kk0 = rem - f * KPU;
        int k = 3 + conv;
        const float* w = (conv == 0) ? w3 : (conv == 1) ? w4 : w5;
        bf16x8 v;
#pragma unroll
        for (int m = 0; m < 8; ++m) {
            int kk = kk0 + m;
            int j = kk / 100, c = kk - j * 100;
            float x = (j < k && c < 100 && kk < 500)
                      ? w[(size_t)f * (k * 1000) + j * 1000 + 900 + c] : 0.f;
            v[m] = (short)f2bf(x);
        }
        *(bf16x8*)(wfpu + e) = v;
        return;
    }
    bid -= WFPB;
    {                                                 // ---- corr weights w[f,0,0:900]
        int e = (bid * 256 + t) * 8;
        int conv = e / (FN_ * KC), seg = e - conv * (FN_ * KC);
        int k = 3 + conv;
        const float* w = (conv == 0) ? w3 : (conv == 1) ? w4 : w5;
        int f = seg / KC, kk0 = seg - f * KC;
        bf16x8 v;
#pragma unroll
        for (int m = 0; m < 8; ++m) {
            int kk = kk0 + m;
            v[m] = (kk < 900) ? (short)f2bf(w[(size_t)f * (k * 1000) + kk]) : (short)0;
        }
        *(bf16x8*)(corrw + e) = v;
    }
}

// ===== corr mini-GEMM (48 blocks x 16 cols, unchanged) =====
__global__ __launch_bounds__(256) void corr_gemm(
    const ushort_t* __restrict__ we_flat, const ushort_t* __restrict__ corrw,
    float* __restrict__ corr_all)
{
    int y = blockIdx.x;
    int t = threadIdx.x;
    int w = t >> 6, lane = t & 63;
    int l15 = lane & 15, lhi = lane >> 4;

    f32x4 acc[2] = {};
    const ushort_t* Bbase = corrw + (size_t)(y << 4) * KC;

    for (int kt = 0; kt < KC / 64; ++kt) {
#pragma unroll
        for (int ks = 0; ks < 2; ++ks) {
            int kk = (kt << 6) + (ks << 5) + (lhi << 3);
            bf16x8 afr[2], bfr;
#pragma unroll
            for (int mf = 0; mf < 2; ++mf) {
                int row = (w << 5) + (mf << 4) + l15;
                afr[mf] = ld8_pair(we_flat + (size_t)row * WE_STRIDE + kk);
            }
            bfr = *(const bf16x8*)(Bbase + (size_t)l15 * KC + kk);
#pragma unroll
            for (int mf = 0; mf < 2; ++mf)
                acc[mf] = __builtin_amdgcn_mfma_f32_16x16x32_bf16(
                    afr[mf], bfr, acc[mf], 0, 0, 0);
        }
    }
#pragma unroll
    for (int mf = 0; mf < 2; ++mf)
#pragma unroll
        for (int j = 0; j < 4; ++j) {
            int b   = (w << 5) + (mf << 4) + (lhi << 2) + j;
            int col = (y << 4) + l15;
            corr_all[(size_t)b * 768 + col] = acc[mf][j];
        }
}

// ===== conv: 3 CONVS PER BLOCK sharing one A-fragment stream.
// grid (b=128, 4 ntile-of-64) = 512 uniform 41-phase blocks, 2 blocks/CU.
// Per phase: 16 A-loads (shared) + 6 B-stage (3 convs, swizzled, 3-ring LDS)
// + 48 MFMA. Single barrier/phase, in-order-audited counted vmcnt.
__global__ __launch_bounds__(256, 2) void conv_fold(
    const ushort_t* __restrict__ we_flat, const ushort_t* __restrict__ posflat,
    const ushort_t* __restrict__ wfwu, const ushort_t* __restrict__ wfpu,
    const float* __restrict__ corr_all,
    const float* __restrict__ cb3, const float* __restrict__ cb4, const float* __restrict__ cb5,
    float* __restrict__ sf)
{
    __shared__ ushort_t sB[3][3][4096];       // [ring][conv][64 filt x 64 k], swizzled
    __shared__ float red[2][64];

    int b   = blockIdx.x;
    int n0c = blockIdx.y << 6;                // filter offset within each conv (0..192)

    int t = threadIdx.x;
    int w = t >> 6, lane = t & 63;
    int wm = w & 1, wn = w >> 1;
    int l15 = lane & 15, lhi = lane >> 4;

    const ushort_t* rowW[4];
    const ushort_t* rowP[4];
#pragma unroll
    for (int mf = 0; mf < 4; ++mf) {
        int row = (wm << 6) + (mf << 4) + l15;
        rowW[mf] = we_flat + (size_t)b * WE_STRIDE  + row * 300;
        rowP[mf] = posflat + (size_t)b * POS_STRIDE + row * 100;
    }

    const char* Bw0 = (const char*)(wfwu + (size_t)n0c * KWU);
    const char* Bp0 = (const char*)(wfpu + (size_t)n0c * KPU);
    // per-conv base advance: conv c word base = Bw0 + c*FN_*KWU*2, pos likewise

#define STAGEB(RING, T)                                                         \
    {                                                                           \
        int isw_ = (T) < NTW;                                                   \
        size_t str_ = isw_ ? (size_t)(KWU * 2) : (size_t)(KPU * 2);             \
        size_t kb_ = (size_t)(isw_ ? (T) : (T) - NTW) << 7;                     \
        _Pragma("unroll")                                                       \
        for (int c = 0; c < 3; ++c) {                                           \
            const char* base_ = (isw_ ? Bw0 : Bp0) +                            \
                (size_t)c * (isw_ ? (FN_ * KWU * 2) : (FN_ * KPU * 2));         \
            _Pragma("unroll")                                                   \
            for (int u = 0; u < 2; ++u) {                                       \
                int ci = (u << 8) + t;                                          \
                int fr = ci >> 3, cin = ci & 7;                                 \
                int sc = cin ^ (fr & 7);                                        \
                gld_lds16(base_ + (size_t)fr * str_ + kb_ + ((size_t)sc << 4),  \
                          (char*)sB + ((((RING) * 3 + c)) << 13) + (ci << 4));  \
            }                                                                   \
        }                                                                       \
    }

#define LOADA(T)                                                                \
    {                                                                           \
        int isw_ = (T) < NTW;                                                   \
        int kb_ = (isw_ ? (T) : (T) - NTW) << 6;                                \
        _Pragma("unroll")                                                       \
        for (int ks = 0; ks < 2; ++ks) {                                        \
            int kk = kb_ + (ks << 5) + (lhi << 3);                              \
            _Pragma("unroll")                                                   \
            for (int mf = 0; mf < 4; ++mf)                                      \
                afr[ks][mf] = ld8_pair((isw_ ? rowW[mf] : rowP[mf]) + kk);      \
        }                                                                       \
    }

    f32x4 acc[3][4][2] = {};
    bf16x8 afr[2][4];

    // prologue queue: [stage0:6][stage1:6][A(0):16]
    STAGEB(0, 0);
    STAGEB(1, 1);
    LOADA(0);

    for (int kt = 0; kt < NT; ++kt) {
        // steady entry queue: [stage(T):6][A(T):16][stage(T+1):6] -> drain stage(T)
        if (kt == NT - 1) { asm volatile("s_waitcnt vmcnt(16)" ::: "memory"); }
        else              { asm volatile("s_waitcnt vmcnt(22)" ::: "memory"); }
        BAR;

        int ring = kt % 3;
#pragma unroll
        for (int ks = 0; ks < 2; ++ks) {
#pragma unroll
            for (int c = 0; c < 3; ++c) {
                bf16x8 bfr[2];
#pragma unroll
                for (int nf = 0; nf < 2; ++nf) {
                    int fr = (wn << 5) + (nf << 4) + l15;
                    int pc = ((ks << 2) + lhi) ^ (fr & 7);
                    bfr[nf] = *(const bf16x8*)&sB[ring][c][fr * 64 + pc * 8];
                }
                __builtin_amdgcn_s_setprio(1);
#pragma unroll
                for (int mf = 0; mf < 4; ++mf)
#pragma unroll
                    for (int nf = 0; nf < 2; ++nf)
                        acc[c][mf][nf] = __builtin_amdgcn_mfma_f32_16x16x32_bf16(
                            afr[ks][mf], bfr[nf], acc[c][mf][nf], 0, 0, 0);
                __builtin_amdgcn_s_setprio(0);
            }
        }
        if (kt + 1 < NT) LOADA(kt + 1);
        if (kt + 2 < NT) STAGEB((kt + 2) % 3, kt + 2);
    }
#undef LOADA
#undef STAGEB

    // ---- epilogue per conv: row-0 corr subtract, masked max, bias+tanh ----
#pragma unroll
    for (int c = 0; c < 3; ++c) {
        const float* bias = (c == 0) ? cb3 : (c == 1) ? cb4 : cb5;
        int M = 126 - c;
#pragma unroll
        for (int nf = 0; nf < 2; ++nf) {
            int col = (wn << 5) + (nf << 4) + l15;
            float bmax = -INFINITY;
#pragma unroll
            for (int mf = 0; mf < 4; ++mf) {
#pragma unroll
                for (int j = 0; j < 4; ++j) {
                    int i = (wm << 6) + (mf << 4) + (lhi << 2) + j;
                    float v = acc[c][mf][nf][j];
                    if (i == 0) v -= corr_all[(size_t)b * 768 + (c << 8) + n0c + col];
                    if (i < M) bmax = fmaxf(bmax, v);
                }
            }
            bmax = fmaxf(bmax, __shfl_xor(bmax, 16));
            bmax = fmaxf(bmax, __shfl_xor(bmax, 32));
            if (lane < 16) red[wm][col] = bmax;
        }
        __syncthreads();
        if (t < 64) {
            float m = fmaxf(red[0][t], red[1][t]);
            sf[(size_t)b * (3 * FN_) + (c << 8) + n0c + t] = tanhf(m + bias[n0c + t]);
        }
        __syncthreads();
    }
}

// ---- tail: span/lex feats + g + final logits, one block per b ----
__device__ __forceinline__ int tok_at(const int* inputs, int b, int idx) {
    return (idx >= 0 && idx < L_) ? inputs[b * L_ + idx] : 0;
}
__global__ __launch_bounds__(256) void tail_kernel(
    const int* __restrict__ inputs,
    const int* __restrict__ e1s, const int* __restrict__ e1e,
    const int* __restrict__ e2s, const int* __restrict__ e2e,
    const float* __restrict__ emb, const float* __restrict__ sf,
    const float* __restrict__ W1, const float* __restrict__ b1,
    const float* __restrict__ W2, const float* __restrict__ b2,
    float* __restrict__ y)
{
    __shared__ float o_loc[1900];
    __shared__ float sfl[3 * FN_];

    int b = blockIdx.x, t = threadIdx.x;
    int lane = t & 63, w = t >> 6;

    for (int k = t; k < 3 * FN_; k += 256) sfl[k] = sf[(size_t)b * (3 * FN_) + k];

    int s1 = e1s[b], t1 = e1e[b], s2 = e2s[b], t2 = e2e[b];
    float inv1 = 1.f / (float)(t1 - s1 + 1);
    float inv2 = 1.f / (float)(t2 - s2 + 1);
    int ta = tok_at(inputs, b, s1 - 1), tb = tok_at(inputs, b, t1 + 1);
    int tc = tok_at(inputs, b, s2 - 1), td = tok_at(inputs, b, t2 + 1);
    for (int d = t; d < E_; d += 256) {
        float s = 0.f;
        for (int p = s1; p <= t1; ++p) s += emb[(size_t)tok_at(inputs, b, p) * E_ + d];
        o_loc[d] = s * inv1;
        s = 0.f;
        for (int p = s2; p <= t2; ++p) s += emb[(size_t)tok_at(inputs, b, p) * E_ + d];
        o_loc[E_ + d] = s * inv2;
        o_loc[2 * E_ + d] = emb[(size_t)ta * E_ + d];
        o_loc[3 * E_ + d] = emb[(size_t)tb * E_ + d];
        o_loc[4 * E_ + d] = emb[(size_t)tc * E_ + d];
        o_loc[5 * E_ + d] = emb[(size_t)td * E_ + d];
    }
    __syncthreads();

    for (int h = w; h < H2_; h += 4) {
        const float* wr = W1 + (size_t)h * (3 * FN_);
        float acc = 0.f;
#pragma unroll
        for (int j = 0; j < 12; ++j) acc += sfl[lane + (j << 6)] * wr[lane + (j << 6)];
        for (int off = 32; off; off >>= 1) acc += __shfl_down(acc, off);
        if (lane == 0) o_loc[1800 + h] = tanhf(acc + b1[h]);
    }
    __syncthreads();

    for (int lab = w; lab < LAB_; lab += 4) {
        const float* wr = W2 + (size_t)lab * 1900;
        float acc = 0.f;
        for (int d = lane; d < 1900; d += 64) acc += o_loc[d] * wr[d];
        for (int off = 32; off; off >>= 1) acc += __shfl_down(acc, off);
        if (lane == 0) y[(size_t)b * LAB_ + lab] = acc + b2[lab];
    }
}

extern "C" void kernel_launch(void* const* d_in, const int* in_sizes, int n_in,
                              void* d_out, int out_size, void* d_ws, size_t ws_size,
                              hipStream_t stream) {
    const int*   inputs = (const int*)d_in[0];
    const int*   e1s    = (const int*)d_in[1];
    const int*   e1e    = (const int*)d_in[2];
    const int*   e2s    = (const int*)d_in[3];
    const int*   e2e    = (const int*)d_in[4];
    const int*   p1     = (const int*)d_in[5];
    const int*   p2     = (const int*)d_in[6];
    const float* emb    = (const float*)d_in[7];
    const float* pos1   = (const float*)d_in[8];
    const float* pos2   = (const float*)d_in[9];
    const float* w3     = (const float*)d_in[10];
    const float* cb3    = (const float*)d_in[11];
    const float* w4     = (const float*)d_in[12];
    const float* cb4    = (const float*)d_in[13];
    const float* w5     = (const float*)d_in[14];
    const float* cb5    = (const float*)d_in[15];
    const float* W1     = (const float*)d_in[16];
    const float* b1     = (const float*)d_in[17];
    const float* W2     = (const float*)d_in[18];
    const float* b2     = (const float*)d_in[19];
    float* y = (float*)d_out;

    char* ws = (char*)d_ws;
    size_t off = 0;
    ushort_t* we_flat = (ushort_t*)(ws + off); off += (size_t)N_WE * 2;
    ushort_t* posflat = (ushort_t*)(ws + off); off += (size_t)N_POS * 2;
    ushort_t* wfwu    = (ushort_t*)(ws + off); off += (size_t)N_WFWU * 2;
    ushort_t* wfpu    = (ushort_t*)(ws + off); off += (size_t)N_WFPU * 2;
    ushort_t* corrw   = (ushort_t*)(ws + off); off += (size_t)N_CORR * 2;
    float*    corr_all= (float*)(ws + off);    off += (size_t)B_ * 768 * 4;
    float*    sf      = (float*)(ws + off);    off += (size_t)B_ * 3 * FN_ * 4;

    setup_kernel<<<dim3(SETUP_BLOCKS), dim3(256), 0, stream>>>(
        inputs, p1, p2, emb, pos1, pos2, w3, w4, w5,
        we_flat, posflat, wfwu, wfpu, corrw);

    corr_gemm<<<dim3(48), dim3(256), 0, stream>>>(we_flat, corrw, corr_all);

    conv_fold<<<dim3(B_, 4), dim3(256), 0, stream>>>(
        we_flat, posflat, wfwu, wfpu, corr_all, cb3, cb4, cb5, sf);

    tail_kernel<<<dim3(B_), dim3(256), 0, stream>>>(
        inputs, e1s, e1e, e2s, e2e, emb, sf, W1, b1, W2, b2, y);
}

// Round 16
// 129.704 us; speedup vs baseline: 1.7856x; 1.3361x over previous
//
#include <hip/hip_runtime.h>
#include <math.h>

#define B_   128
#define L_   128
#define E_   300
#define P_   50
#define FN_  256
#define H2_  100
#define LAB_ 19

typedef unsigned short ushort_t;
typedef __attribute__((ext_vector_type(8))) short bf16x8;
typedef __attribute__((ext_vector_type(4))) short bf16x4;
typedef __attribute__((ext_vector_type(4))) short short4v;
typedef __attribute__((ext_vector_type(4))) float f32x4;

// Unified folded geometry: all convs share A. Word KWU=2112, pos KPU=512, corr K=960.
#define KWU 2112
#define KPU 512
#define KC  960
#define NTW 33
#define NTP 8
#define NT  41

#define WE_STRIDE  40960
#define POS_STRIDE 13312

#define N_WE    (B_ * WE_STRIDE)
#define N_POS   (B_ * POS_STRIDE)
#define N_WFWU  (3 * FN_ * KWU)
#define N_WFPU  (3 * FN_ * KPU)
#define N_CORR  (3 * FN_ * KC)

#define WEB   (B_ * 35)
#define POSB  (B_ * 17)
#define WFWB  (N_WFWU / 2048)
#define WFPB  (N_WFPU / 2048)
#define CORB  (N_CORR / 2048)
#define SETUP_BLOCKS (WEB + POSB + WFWB + WFPB + CORB)

__device__ __forceinline__ ushort_t f2bf(float x) {
    unsigned u = __float_as_uint(x);
    u += 0x7FFFu + ((u >> 16) & 1u);
    return (ushort_t)(u >> 16);
}

__device__ __forceinline__ void gld_lds16(const void* g, void* lds_uniform) {
    __builtin_amdgcn_global_load_lds(
        (const __attribute__((address_space(1))) void*)g,
        (__attribute__((address_space(3))) void*)lds_uniform,
        16, 0, 0);
}

// 8 bf16 via two 8B loads (rows stride 600/200B: only 8B-aligned)
__device__ __forceinline__ bf16x8 ld8_pair(const ushort_t* p) {
    bf16x4 lo = *(const bf16x4*)p;
    bf16x4 hi = *(const bf16x4*)(p + 4);
    return __builtin_shufflevector(lo, hi, 0, 1, 2, 3, 4, 5, 6, 7);
}

#define MEMFENCE asm volatile("" ::: "memory")
#define BAR      do { MEMFENCE; __builtin_amdgcn_s_barrier(); MEMFENCE; } while (0)

// ================= setup (unchanged from R15) =========
__global__ __launch_bounds__(256) void setup_kernel(
    const int* __restrict__ inputs, const int* __restrict__ p1, const int* __restrict__ p2,
    const float* __restrict__ emb, const float* __restrict__ pos1, const float* __restrict__ pos2,
    const float* __restrict__ w3, const float* __restrict__ w4, const float* __restrict__ w5,
    ushort_t* __restrict__ we_flat, ushort_t* __restrict__ posflat,
    ushort_t* __restrict__ wfwu, ushort_t* __restrict__ wfpu, ushort_t* __restrict__ corrw)
{
    int bid = blockIdx.x, t = threadIdx.x;

    if (bid < WEB) {                                  // ---- we_flat
        int b = bid / 35, rb = bid - b * 35;
        int r = rb * 4 + (t >> 6), c8 = t & 63;
        if (c8 >= 38) return;
        int e0 = c8 * 8;
        int n = (e0 + 8 <= 300) ? 8 : 300 - e0;
        int flat = r * 300 + e0;
        ushort_t* dst = we_flat + (size_t)b * WE_STRIDE + flat;
        if (r < 130) {
            int tok = (r == 0 || r == 129) ? 0 : inputs[b * L_ + r - 1];
            const float* er = emb + (size_t)tok * 300 + e0;
            short4v v0, v1;
#pragma unroll
            for (int m = 0; m < 4; ++m) v0[m] = (short)f2bf(er[m]);
            *(short4v*)dst = v0;
            if (n == 8) {
#pragma unroll
                for (int m = 0; m < 4; ++m) v1[m] = (short)f2bf(er[4 + m]);
                *(short4v*)(dst + 4) = v1;
            }
        } else {
            short4v z = {0, 0, 0, 0};
            if (flat + 4 <= WE_STRIDE) *(short4v*)dst = z;
            if (n == 8 && flat + 8 <= WE_STRIDE) *(short4v*)(dst + 4) = z;
        }
        return;
    }
    bid -= WEB;
    if (bid < POSB) {                                 // ---- posflat
        int b = bid / 17, rb = bid - b * 17;
        int r = rb * 8 + (t >> 5), c = t & 31;
        if (c >= 25) return;
        int e0 = c * 4;
        int flat = r * 100 + e0;
        ushort_t* dst = posflat + (size_t)b * POS_STRIDE + flat;
        short4v v;
        if (r < 128) {
            int pp1 = p1[b * L_ + r], pp2 = p2[b * L_ + r];
#pragma unroll
            for (int m = 0; m < 4; ++m) {
                int d = e0 + m;
                float x = (d < 50) ? pos1[(size_t)pp1 * 50 + d]
                                   : pos2[(size_t)pp2 * 50 + (d - 50)];
                v[m] = (short)f2bf(x);
            }
            *(short4v*)dst = v;
        } else {
            short4v z = {0, 0, 0, 0};
            if (flat + 4 <= POS_STRIDE) *(short4v*)dst = z;
        }
        return;
    }
    bid -= POSB;
    if (bid < WFWB) {                                 // ---- unified folded word weights
        int e = (bid * 256 + t) * 8;
        int conv = e / (FN_ * KWU);
        int rem  = e - conv * (FN_ * KWU);
        int f = rem / KWU, kk0 = rem - f * KWU;
        int k = 3 + conv;
        const float* w = (conv == 0) ? w3 : (conv == 1) ? w4 : w5;
        bf16x8 v;
#pragma unroll
        for (int m = 0; m < 8; ++m) {
            int kk = kk0 + m;
            float s = 0.f;
            if (kk < (k + 2) * 300) {
                int mr = kk / 300, c = kk - mr * 300;
                int jlo = (mr - 2 < 0) ? 0 : mr - 2;
                int jhi = (mr < k - 1) ? mr : k - 1;
                for (int j = jlo; j <= jhi; ++j)
                    s += w[(size_t)f * (k * 1000) + j * 1000 + (mr - j) * 300 + c];
            }
            v[m] = (short)f2bf(s);
        }
        *(bf16x8*)(wfwu + e) = v;
        return;
    }
    bid -= WFWB;
    if (bid < WFPB) {                                 // ---- unified pos weights
        int e = (bid * 256 + t) * 8;
        int conv = e / (FN_ * KPU);
        int rem  = e - conv * (FN_ * KPU);
        int f = rem / KPU, kk0 = rem - f * KPU;
        int k = 3 + conv;
        const float* w = (conv == 0) ? w3 : (conv == 1) ? w4 : w5;
        bf16x8 v;
#pragma unroll
        for (int m = 0; m < 8; ++m) {
            int kk = kk0 + m;
            int j = kk / 100, c = kk - j * 100;
            float x = (j < k && c < 100 && kk < 500)
                      ? w[(size_t)f * (k * 1000) + j * 1000 + 900 + c] : 0.f;
            v[m] = (short)f2bf(x);
        }
        *(bf16x8*)(wfpu + e) = v;
        return;
    }
    bid -= WFPB;
    {                                                 // ---- corr weights w[f,0,0:900]
        int e = (bid * 256 + t) * 8;
        int conv = e / (FN_ * KC), seg = e - conv * (FN_ * KC);
        int k = 3 + conv;
        const float* w = (conv == 0) ? w3 : (conv == 1) ? w4 : w5;
        int f = seg / KC, kk0 = seg - f * KC;
        bf16x8 v;
#pragma unroll
        for (int m = 0; m < 8; ++m) {
            int kk = kk0 + m;
            v[m] = (kk < 900) ? (short)f2bf(w[(size_t)f * (k * 1000) + kk]) : (short)0;
        }
        *(bf16x8*)(corrw + e) = v;
    }
}

// ===== corr mini-GEMM (48 blocks x 16 cols, unchanged) =====
__global__ __launch_bounds__(256) void corr_gemm(
    const ushort_t* __restrict__ we_flat, const ushort_t* __restrict__ corrw,
    float* __restrict__ corr_all)
{
    int y = blockIdx.x;
    int t = threadIdx.x;
    int w = t >> 6, lane = t & 63;
    int l15 = lane & 15, lhi = lane >> 4;

    f32x4 acc[2] = {};
    const ushort_t* Bbase = corrw + (size_t)(y << 4) * KC;

    for (int kt = 0; kt < KC / 64; ++kt) {
#pragma unroll
        for (int ks = 0; ks < 2; ++ks) {
            int kk = (kt << 6) + (ks << 5) + (lhi << 3);
            bf16x8 afr[2], bfr;
#pragma unroll
            for (int mf = 0; mf < 2; ++mf) {
                int row = (w << 5) + (mf << 4) + l15;
                afr[mf] = ld8_pair(we_flat + (size_t)row * WE_STRIDE + kk);
            }
            bfr = *(const bf16x8*)(Bbase + (size_t)l15 * KC + kk);
#pragma unroll
            for (int mf = 0; mf < 2; ++mf)
                acc[mf] = __builtin_amdgcn_mfma_f32_16x16x32_bf16(
                    afr[mf], bfr, acc[mf], 0, 0, 0);
        }
    }
#pragma unroll
    for (int mf = 0; mf < 2; ++mf)
#pragma unroll
        for (int j = 0; j < 4; ++j) {
            int b   = (w << 5) + (mf << 4) + (lhi << 2) + j;
            int col = (y << 4) + l15;
            corr_all[(size_t)b * 768 + col] = acc[mf][j];
        }
}

// ===== conv: TWO BATCHES per block, 3 convs share A-fragment stream.
// 512 thr = 8 waves (2b x 2m x 2n). grid (64 b-pairs, 4 ntile) = 256 = 1/CU.
// B panel amortized over 2 b's: L2 bytes/phase-CU 112 -> 88 KB.
// 3-ring LDS, single barrier/phase, in-order vmcnt: steady 19, tail 16.
__global__ __launch_bounds__(512, 2) void conv_fold(
    const ushort_t* __restrict__ we_flat, const ushort_t* __restrict__ posflat,
    const ushort_t* __restrict__ wfwu, const ushort_t* __restrict__ wfpu,
    const float* __restrict__ corr_all,
    const float* __restrict__ cb3, const float* __restrict__ cb4, const float* __restrict__ cb5,
    float* __restrict__ sf)
{
    __shared__ ushort_t sB[3][3][4096];       // [ring][conv][64 filt x 64 k], swizzled
    __shared__ float red[2][2][64];           // [bhalf][wm][col]

    int b0  = blockIdx.x << 1;
    int n0c = blockIdx.y << 6;

    int t = threadIdx.x;
    int w = t >> 6, lane = t & 63;
    int wb = w & 1, wm = (w >> 1) & 1, wn = w >> 2;
    int l15 = lane & 15, lhi = lane >> 4;
    int b = b0 + wb;

    const ushort_t* rowW[4];
    const ushort_t* rowP[4];
#pragma unroll
    for (int mf = 0; mf < 4; ++mf) {
        int row = (wm << 6) + (mf << 4) + l15;
        rowW[mf] = we_flat + (size_t)b * WE_STRIDE  + row * 300;
        rowP[mf] = posflat + (size_t)b * POS_STRIDE + row * 100;
    }

    const char* Bw0 = (const char*)(wfwu + (size_t)n0c * KWU);
    const char* Bp0 = (const char*)(wfpu + (size_t)n0c * KPU);

#define STAGEB(RING, T)                                                         \
    {                                                                           \
        int isw_ = (T) < NTW;                                                   \
        size_t str_ = isw_ ? (size_t)(KWU * 2) : (size_t)(KPU * 2);             \
        size_t kb_ = (size_t)(isw_ ? (T) : (T) - NTW) << 7;                     \
        _Pragma("unroll")                                                       \
        for (int c = 0; c < 3; ++c) {                                           \
            const char* base_ = (isw_ ? Bw0 : Bp0) +                            \
                (size_t)c * (isw_ ? (FN_ * KWU * 2) : (FN_ * KPU * 2));         \
            int fr = t >> 3, cin = t & 7;                                       \
            int sc = cin ^ (fr & 7);                                            \
            gld_lds16(base_ + (size_t)fr * str_ + kb_ + ((size_t)sc << 4),      \
                      (char*)sB + (((RING) * 3 + c) << 13) + (t << 4));         \
        }                                                                       \
    }

#define LOADA(T)                                                                \
    {                                                                           \
        int isw_ = (T) < NTW;                                                   \
        int kb_ = (isw_ ? (T) : (T) - NTW) << 6;                                \
        _Pragma("unroll")                                                       \
        for (int ks = 0; ks < 2; ++ks) {                                        \
            int kk = kb_ + (ks << 5) + (lhi << 3);                              \
            _Pragma("unroll")                                                   \
            for (int mf = 0; mf < 4; ++mf)                                      \
                afr[ks][mf] = ld8_pair((isw_ ? rowW[mf] : rowP[mf]) + kk);      \
        }                                                                       \
    }

    f32x4 acc[3][4][2] = {};
    bf16x8 afr[2][4];

    // prologue queue: [stage0:3][stage1:3][A(0):16]
    STAGEB(0, 0);
    STAGEB(1, 1);
    LOADA(0);

    for (int kt = 0; kt < NT; ++kt) {
        // steady entry queue: [stage(T):3][A(T):16][stage(T+1):3] -> drain stage(T)
        if (kt == NT - 1) { asm volatile("s_waitcnt vmcnt(16)" ::: "memory"); }
        else              { asm volatile("s_waitcnt vmcnt(19)" ::: "memory"); }
        BAR;

        int ring = kt % 3;
#pragma unroll
        for (int ks = 0; ks < 2; ++ks) {
#pragma unroll
            for (int c = 0; c < 3; ++c) {
                bf16x8 bfr[2];
#pragma unroll
                for (int nf = 0; nf < 2; ++nf) {
                    int fr = (wn << 5) + (nf << 4) + l15;
                    int pc = ((ks << 2) + lhi) ^ (fr & 7);
                    bfr[nf] = *(const bf16x8*)&sB[ring][c][fr * 64 + pc * 8];
                }
                __builtin_amdgcn_s_setprio(1);
#pragma unroll
                for (int mf = 0; mf < 4; ++mf)
#pragma unroll
                    for (int nf = 0; nf < 2; ++nf)
                        acc[c][mf][nf] = __builtin_amdgcn_mfma_f32_16x16x32_bf16(
                            afr[ks][mf], bfr[nf], acc[c][mf][nf], 0, 0, 0);
                __builtin_amdgcn_s_setprio(0);
            }
        }
        if (kt + 1 < NT) LOADA(kt + 1);
        if (kt + 2 < NT) STAGEB((kt + 2) % 3, kt + 2);
    }
#undef LOADA
#undef STAGEB

    // ---- epilogue per conv: row-0 corr subtract, masked max, bias+tanh ----
#pragma unroll
    for (int c = 0; c < 3; ++c) {
        const float* bias = (c == 0) ? cb3 : (c == 1) ? cb4 : cb5;
        int M = 126 - c;
#pragma unroll
        for (int nf = 0; nf < 2; ++nf) {
            int col = (wn << 5) + (nf << 4) + l15;
            float bmax = -INFINITY;
#pragma unroll
            for (int mf = 0; mf < 4; ++mf) {
#pragma unroll
                for (int j = 0; j < 4; ++j) {
                    int i = (wm << 6) + (mf << 4) + (lhi << 2) + j;
                    float v = acc[c][mf][nf][j];
                    if (i == 0) v -= corr_all[(size_t)b * 768 + (c << 8) + n0c + col];
                    if (i < M) bmax = fmaxf(bmax, v);
                }
            }
            bmax = fmaxf(bmax, __shfl_xor(bmax, 16));
            bmax = fmaxf(bmax, __shfl_xor(bmax, 32));
            if (lane < 16) red[wb][wm][col] = bmax;
        }
        __syncthreads();
        if (t < 128) {
            int bh = t >> 6, col = t & 63;
            float m = fmaxf(red[bh][0][col], red[bh][1][col]);
            sf[(size_t)(b0 + bh) * (3 * FN_) + (c << 8) + n0c + col] = tanhf(m + bias[n0c + col]);
        }
        __syncthreads();
    }
}

// ---- tail: 512 thr, float4-vectorized dots ----
__device__ __forceinline__ int tok_at(const int* inputs, int b, int idx) {
    return (idx >= 0 && idx < L_) ? inputs[b * L_ + idx] : 0;
}
__global__ __launch_bounds__(512) void tail_kernel(
    const int* __restrict__ inputs,
    const int* __restrict__ e1s, const int* __restrict__ e1e,
    const int* __restrict__ e2s, const int* __restrict__ e2e,
    const float* __restrict__ emb, const float* __restrict__ sf,
    const float* __restrict__ W1, const float* __restrict__ b1,
    const float* __restrict__ W2, const float* __restrict__ b2,
    float* __restrict__ y)
{
    __shared__ __align__(16) float o_loc[1900];
    __shared__ __align__(16) float sfl[3 * FN_];

    int b = blockIdx.x, t = threadIdx.x;
    int lane = t & 63, w = t >> 6;

    for (int k = t; k < 3 * FN_; k += 512) sfl[k] = sf[(size_t)b * (3 * FN_) + k];

    int s1 = e1s[b], t1 = e1e[b], s2 = e2s[b], t2 = e2e[b];
    float inv1 = 1.f / (float)(t1 - s1 + 1);
    float inv2 = 1.f / (float)(t2 - s2 + 1);
    int ta = tok_at(inputs, b, s1 - 1), tb = tok_at(inputs, b, t1 + 1);
    int tc = tok_at(inputs, b, s2 - 1), td = tok_at(inputs, b, t2 + 1);
    for (int d = t; d < E_; d += 512) {
        float s = 0.f;
        for (int p = s1; p <= t1; ++p) s += emb[(size_t)tok_at(inputs, b, p) * E_ + d];
        o_loc[d] = s * inv1;
        s = 0.f;
        for (int p = s2; p <= t2; ++p) s += emb[(size_t)tok_at(inputs, b, p) * E_ + d];
        o_loc[E_ + d] = s * inv2;
        o_loc[2 * E_ + d] = emb[(size_t)ta * E_ + d];
        o_loc[3 * E_ + d] = emb[(size_t)tb * E_ + d];
        o_loc[4 * E_ + d] = emb[(size_t)tc * E_ + d];
        o_loc[5 * E_ + d] = emb[(size_t)td * E_ + d];
    }
    __syncthreads();

    // g = tanh(sfl @ W1.T + b1): 8-way h-parallel, float4 dots (768 = 3 x 64 x 4)
    const float4* sfl4 = (const float4*)sfl;
    for (int h = w; h < H2_; h += 8) {
        const float4* wr4 = (const float4*)(W1 + (size_t)h * (3 * FN_));
        float acc = 0.f;
#pragma unroll
        for (int j = 0; j < 3; ++j) {
            float4 a = wr4[lane + (j << 6)];
            float4 s = sfl4[lane + (j << 6)];
            acc += a.x * s.x + a.y * s.y + a.z * s.z + a.w * s.w;
        }
        for (int off = 32; off; off >>= 1) acc += __shfl_down(acc, off);
        if (lane == 0) o_loc[1800 + h] = tanhf(acc + b1[h]);
    }
    __syncthreads();

    // y = o_loc @ W2.T + b2: 8-way lab-parallel, float4 dots (1900 = 475 x 4)
    const float4* o4 = (const float4*)o_loc;
    for (int lab = w; lab < LAB_; lab += 8) {
        const float4* wr4 = (const float4*)(W2 + (size_t)lab * 1900);
        float acc = 0.f;
        for (int j = lane; j < 475; j += 64) {
            float4 a = wr4[j];
            float4 o = o4[j];
            acc += a.x * o.x + a.y * o.y + a.z * o.z + a.w * o.w;
        }
        for (int off = 32; off; off >>= 1) acc += __shfl_down(acc, off);
        if (lane == 0) y[(size_t)b * LAB_ + lab] = acc + b2[lab];
    }
}

extern "C" void kernel_launch(void* const* d_in, const int* in_sizes, int n_in,
                              void* d_out, int out_size, void* d_ws, size_t ws_size,
                              hipStream_t stream) {
    const int*   inputs = (const int*)d_in[0];
    const int*   e1s    = (const int*)d_in[1];
    const int*   e1e    = (const int*)d_in[2];
    const int*   e2s    = (const int*)d_in[3];
    const int*   e2e    = (const int*)d_in[4];
    const int*   p1     = (const int*)d_in[5];
    const int*   p2     = (const int*)d_in[6];
    const float* emb    = (const float*)d_in[7];
    const float* pos1   = (const float*)d_in[8];
    const float* pos2   = (const float*)d_in[9];
    const float* w3     = (const float*)d_in[10];
    const float* cb3    = (const float*)d_in[11];
    const float* w4     = (const float*)d_in[12];
    const float* cb4    = (const float*)d_in[13];
    const float* w5     = (const float*)d_in[14];
    const float* cb5    = (const float*)d_in[15];
    const float* W1     = (const float*)d_in[16];
    const float* b1     = (const float*)d_in[17];
    const float* W2     = (const float*)d_in[18];
    const float* b2     = (const float*)d_in[19];
    float* y = (float*)d_out;

    char* ws = (char*)d_ws;
    size_t off = 0;
    ushort_t* we_flat = (ushort_t*)(ws + off); off += (size_t)N_WE * 2;
    ushort_t* posflat = (ushort_t*)(ws + off); off += (size_t)N_POS * 2;
    ushort_t* wfwu    = (ushort_t*)(ws + off); off += (size_t)N_WFWU * 2;
    ushort_t* wfpu    = (ushort_t*)(ws + off); off += (size_t)N_WFPU * 2;
    ushort_t* corrw   = (ushort_t*)(ws + off); off += (size_t)N_CORR * 2;
    float*    corr_all= (float*)(ws + off);    off += (size_t)B_ * 768 * 4;
    float*    sf      = (float*)(ws + off);    off += (size_t)B_ * 3 * FN_ * 4;

    setup_kernel<<<dim3(SETUP_BLOCKS), dim3(256), 0, stream>>>(
        inputs, p1, p2, emb, pos1, pos2, w3, w4, w5,
        we_flat, posflat, wfwu, wfpu, corrw);

    corr_gemm<<<dim3(48), dim3(256), 0, stream>>>(we_flat, corrw, corr_all);

    conv_fold<<<dim3(B_ / 2, 4), dim3(512), 0, stream>>>(
        we_flat, posflat, wfwu, wfpu, corr_all, cb3, cb4, cb5, sf);

    tail_kernel<<<dim3(B_), dim3(512), 0, stream>>>(
        inputs, e1s, e1e, e2s, e2e, emb, sf, W1, b1, W2, b2, y);
}